// Round 3
// baseline (94.044 us; speedup 1.0000x reference)
//
#include <hip/hip_runtime.h>
#include <hip/hip_bf16.h>
#include <math.h>

#define TOKS 16384
#define CDIM 1024
#define NEXP 8
#define RDIM 64
#define CAP  TOKS
#define NBLK_R 1024   // router blocks (16 tokens each)
#define FT_MAX 320    // max fused tiles: 16384/64 + 64 partials

using f32x4   = __attribute__((ext_vector_type(4))) float;
using bf16x8  = __attribute__((ext_vector_type(8))) short;
using ushort8 = __attribute__((ext_vector_type(8))) unsigned short;

__device__ __forceinline__ ushort f2bf(float f) {
  unsigned u = __builtin_bit_cast(unsigned, f);
  u += 0x7fffu + ((u >> 16) & 1u);   // round-to-nearest-even
  return (ushort)(u >> 16);
}

// ---- pre-pass: rw permute (router-coalesced), Wd->wdt[e][r][k], Wu->wut[e][c][r]
__global__ __launch_bounds__(256) void convert_kernel(
    const float* __restrict__ Wd, const float* __restrict__ Wu,
    const float* __restrict__ rw_all, const int* __restrict__ key_id,
    ushort* __restrict__ wdt, ushort* __restrict__ wut,
    float* __restrict__ rw_p) {
  const int t = blockIdx.x * 256 + threadIdx.x;
  if (t < 2048) {              // rw_p: one float4 per thread
    const int st = t >> 7, rem = t & 127;
    const int h = rem >> 6, l = rem & 63;
    const int C = (st >> 2) * 256 + l * 4 + (st & 3);
    const float4 v = *(const float4*)(rw_all + (size_t)key_id[0] * CDIM * NEXP
                                      + C * 8 + h * 4);
    ((float4*)rw_p)[t] = v;
  } else if (t < 133120) {     // Wd: (e, r, k4)
    const int u = t - 2048;
    const int k4 = u & 255, r = (u >> 8) & 63, e = u >> 14;
    ushort4 h;
    h.x = f2bf(Wd[(size_t)(e * 1024 + k4 * 4 + 0) * 64 + r]);
    h.y = f2bf(Wd[(size_t)(e * 1024 + k4 * 4 + 1) * 64 + r]);
    h.z = f2bf(Wd[(size_t)(e * 1024 + k4 * 4 + 2) * 64 + r]);
    h.w = f2bf(Wd[(size_t)(e * 1024 + k4 * 4 + 3) * 64 + r]);
    ((ushort4*)wdt)[(e * 64 + r) * 256 + k4] = h;
  } else {                     // Wu: (e, c, r4)
    const int u = t - 133120;
    const int r4 = u & 15, c = (u >> 4) & 1023, e = u >> 14;
    ushort4 h;
    h.x = f2bf(Wu[(size_t)(e * 64 + r4 * 4 + 0) * 1024 + c]);
    h.y = f2bf(Wu[(size_t)(e * 64 + r4 * 4 + 1) * 1024 + c]);
    h.z = f2bf(Wu[(size_t)(e * 64 + r4 * 4 + 2) * 1024 + c]);
    h.w = f2bf(Wu[(size_t)(e * 64 + r4 * 4 + 3) * 1024 + c]);
    ((ushort4*)wut)[(e * 1024 + c) * 16 + r4] = h;
  }
}

// ---------------- router: wave = token; NO global atomics ------------------
__global__ __launch_bounds__(256) void router_kernel(
    const float* __restrict__ x, const float* __restrict__ rw_p,
    const float* __restrict__ rb_all, const int* __restrict__ key_id,
    float* __restrict__ imp_part,
    int* __restrict__ pbuf, float2* __restrict__ ggbuf,
    int* __restrict__ histT, ushort* __restrict__ xb) {
  __shared__ float s_imp[4][NEXP];
  __shared__ int   s_pb[16];
  __shared__ float s_g1[16], s_g2[16];
  const int tid = threadIdx.x;
  const int lane = tid & 63;
  const int wave = tid >> 6;
  const int kid = key_id[0];
  const float4* rwp4 = (const float4*)rw_p;
  const float* rb = rb_all + (size_t)kid * NEXP;
  const int eln = ((lane & 1) << 2) | (lane & 2) | ((lane >> 2) & 1);
  const float rbe = rb[eln];
  float impacc = 0.f;

  const int wg = blockIdx.x * 4 + wave;
#pragma unroll 1
  for (int tt = 0; tt < 4; ++tt) {
    const int token = wg * 4 + tt;
    const float* xr = x + (size_t)token * CDIM + lane * 4;
    float4 xv[4];
#pragma unroll
    for (int j = 0; j < 4; ++j) xv[j] = *(const float4*)(xr + j * 256);
    ushort* xo = xb + (size_t)token * CDIM + lane * 4;
#pragma unroll
    for (int j = 0; j < 4; ++j) {
      ushort4 h;
      h.x = f2bf(xv[j].x); h.y = f2bf(xv[j].y);
      h.z = f2bf(xv[j].z); h.w = f2bf(xv[j].w);
      *(ushort4*)(xo + j * 256) = h;
    }
    float acc[8];
#pragma unroll
    for (int e = 0; e < 8; ++e) acc[e] = 0.f;
#pragma unroll
    for (int j = 0; j < 4; ++j) {
#pragma unroll
      for (int i = 0; i < 4; ++i) {
        const int st = j * 4 + i;
        const float4 wA = rwp4[st * 128 + lane];
        const float4 wB = rwp4[st * 128 + 64 + lane];
        const float xi = (&xv[j].x)[i];
        acc[0] = fmaf(xi, wA.x, acc[0]);
        acc[1] = fmaf(xi, wA.y, acc[1]);
        acc[2] = fmaf(xi, wA.z, acc[2]);
        acc[3] = fmaf(xi, wA.w, acc[3]);
        acc[4] = fmaf(xi, wB.x, acc[4]);
        acc[5] = fmaf(xi, wB.y, acc[5]);
        acc[6] = fmaf(xi, wB.z, acc[6]);
        acc[7] = fmaf(xi, wB.w, acc[7]);
      }
    }
    // butterfly 8 accs -> 1 (expert = bitrev3(lane&7)), then 64-lane sum
#pragma unroll
    for (int i = 0; i < 4; ++i) {
      const float send = (lane & 1) ? acc[i] : acc[i + 4];
      const float recv = __shfl_xor(send, 1);
      acc[i] = ((lane & 1) ? acc[i + 4] : acc[i]) + recv;
    }
#pragma unroll
    for (int i = 0; i < 2; ++i) {
      const float send = (lane & 2) ? acc[i] : acc[i + 2];
      const float recv = __shfl_xor(send, 2);
      acc[i] = ((lane & 2) ? acc[i + 2] : acc[i]) + recv;
    }
    {
      const float send = (lane & 4) ? acc[0] : acc[1];
      const float recv = __shfl_xor(send, 4);
      acc[0] = ((lane & 4) ? acc[1] : acc[0]) + recv;
    }
    float v = acc[0];
    v += __shfl_xor(v, 8); v += __shfl_xor(v, 16); v += __shfl_xor(v, 32);

    const float logit = v + rbe;
    float mx = logit;
    mx = fmaxf(mx, __shfl_xor(mx, 1));
    mx = fmaxf(mx, __shfl_xor(mx, 2));
    mx = fmaxf(mx, __shfl_xor(mx, 4));
    const float ex = expf(logit - mx);
    float sm = ex;
    sm += __shfl_xor(sm, 1); sm += __shfl_xor(sm, 2); sm += __shfl_xor(sm, 4);
    const float p = ex / sm;
    float bv = p; int bi = eln;
#pragma unroll
    for (int mk = 1; mk <= 4; mk <<= 1) {
      const float ov = __shfl_xor(bv, mk);
      const int oi = __shfl_xor(bi, mk);
      if (ov > bv || (ov == bv && oi < bi)) { bv = ov; bi = oi; }
    }
    const int e1 = bi; const float v1 = bv;
    float cv = (eln == e1) ? -1.f : p; int ci = eln;
#pragma unroll
    for (int mk = 1; mk <= 4; mk <<= 1) {
      const float ov = __shfl_xor(cv, mk);
      const int oi = __shfl_xor(ci, mk);
      if (ov > cv || (ov == cv && oi < ci)) { cv = ov; ci = oi; }
    }
    const int e2 = ci; const float v2 = cv;

    if (lane == 0) {
      const float gs = 1.f / (v1 + v2);
      const int li = wave * 4 + tt;
      s_g1[li] = v1 * gs;
      s_g2[li] = v2 * gs;
      s_pb[li] = e1 * 8 + e2;
    }
    impacc += p;
  }
  if (lane < 8) s_imp[wave][eln] = impacc;
  __syncthreads();
  if (tid < 8)
    imp_part[blockIdx.x * 8 + tid] =
        s_imp[0][tid] + s_imp[1][tid] + s_imp[2][tid] + s_imp[3][tid];

  // per-token records (coalesced, block-contiguous)
  if (tid < 16) {
    pbuf[blockIdx.x * 16 + tid] = s_pb[tid];
    ggbuf[blockIdx.x * 16 + tid] = make_float2(s_g1[tid], s_g2[tid]);
  }
  // transposed histograms: histT[c*1024 + blk], c in [0,80)
  if (tid < 80) {
    int c = 0;
    if (tid < 16) {
      const int k = tid >> 3, e = tid & 7;
#pragma unroll
      for (int j = 0; j < 16; ++j)
        c += ((k ? (s_pb[j] & 7) : (s_pb[j] >> 3)) == e) ? 1 : 0;
    } else {
      const int b = tid - 16;
#pragma unroll
      for (int j = 0; j < 16; ++j) c += (s_pb[j] == b) ? 1 : 0;
    }
    histT[tid * 1024 + blockIdx.x] = c;
  }
}

// -------- scan: one block per counter, parallel prefix over 1024 blocks ----
__global__ __launch_bounds__(256) void scan_kernel(
    const int* __restrict__ histT, int* __restrict__ baseT,
    int* __restrict__ cnt, int* __restrict__ cnt_pair) {
  __shared__ int ls[256];
  const int c = blockIdx.x;
  const int t = threadIdx.x;
  const int4 v = ((const int4*)(histT + (c << 10)))[t];
  const int s = v.x + v.y + v.z + v.w;
  ls[t] = s;
  __syncthreads();
#pragma unroll
  for (int off = 1; off < 256; off <<= 1) {
    const int add = (t >= off) ? ls[t - off] : 0;
    __syncthreads();
    ls[t] += add;
    __syncthreads();
  }
  const int incl = ls[t];
  const int excl = incl - s;
  int4 b;
  b.x = excl;
  b.y = excl + v.x;
  b.z = excl + v.x + v.y;
  b.w = excl + v.x + v.y + v.z;
  ((int4*)(baseT + (c << 10)))[t] = b;
  if (t == 255) {
    if (c < 16) cnt[c * 32] = incl;
    else        cnt_pair[(c - 16) * 32] = incl;
  }
}

// -------- scatter (blocks 0..255) + plan (block 256) -----------------------
__global__ __launch_bounds__(256) void scatter_kernel(
    const int* __restrict__ baseT, const int* __restrict__ pbuf,
    const int* __restrict__ cnt_pair,
    int* __restrict__ pairlist, int* __restrict__ fplan,
    int* __restrict__ totals) {
  if (blockIdx.x == 256) {   // plan: 64-token tiles per pair bucket
    __shared__ int uoff[64];
    const int t = threadIdx.x;
    if (t == 0) {
      int a = 0;
      for (int b = 0; b < 64; ++b) { uoff[b] = a; a += (cnt_pair[b * 32] + 63) >> 6; }
      totals[1] = a;
    }
    __syncthreads();
    if (t < 64) {
      const int nb = (cnt_pair[t * 32] + 63) >> 6;
      for (int i = 0; i < nb; ++i) fplan[uoff[t] + i] = (t << 16) | i;
    }
    return;
  }
  const int tid = threadIdx.x;
  const int lane = tid & 63;
  const int wave = tid >> 6;
  const int rb = blockIdx.x * 4 + wave;   // router block, 0..1023
  const int i = lane;
  int pb = 0;
  if (lane < 16) pb = pbuf[rb * 16 + lane];
  int rp = 0;
#pragma unroll
  for (int j = 0; j < 15; ++j) {
    const int q = __shfl(pb, j);
    if (j < i) rp += (q == pb) ? 1 : 0;
  }
  if (lane < 16) {
    const int token = rb * 16 + i;
    const int sp = baseT[((16 + pb) << 10) + rb] + rp;
    pairlist[pb * CAP + sp] = token;
  }
}

// ---- fused expert: per 64-token pair tile, down(GELU,gate) -> up -> out ----
// Phase 1: H0|H1 = GELU(x@Wd_e1)*g1 | GELU(x@Wd_e2)*g2   (M=64, N=128, K=1024)
// Phase 2: for 8 col slices: out = H0@WuA + H1@WuB        (M=64, N=128, K=64+64)
__global__ __launch_bounds__(256) void expert_kernel(
    const ushort* __restrict__ xb, const ushort* __restrict__ wdt,
    const ushort* __restrict__ wut,
    const int* __restrict__ cnt_pair, const int* __restrict__ pairlist,
    const float2* __restrict__ ggbuf,
    const int* __restrict__ fplan, const int* __restrict__ totals,
    float* __restrict__ out) {
  if (blockIdx.x >= totals[1]) return;
  const int ent = fplan[blockIdx.x];
  const int b = ent >> 16, tile = ent & 0xffff;
  const int ea = b >> 3, eb = b & 7;
  const int n = cnt_pair[b * 32];
  const int start = tile * 64;

  __shared__ __align__(16) char smem[50176];
  ushort* As  = (ushort*)(smem);            // 8 KB  phase1 (aliased by BuA)
  ushort* BsA = (ushort*)(smem + 8192);     // 8 KB  phase1
  ushort* BsB = (ushort*)(smem + 16384);    // 8 KB  phase1
  ushort* BuA = (ushort*)(smem);            // 16 KB phase2
  ushort* BuB = (ushort*)(smem + 16384);    // 16 KB phase2
  ushort* Hs0 = (ushort*)(smem + 32768);    // 8 KB
  ushort* Hs1 = (ushort*)(smem + 40960);    // 8 KB
  int*   toks = (int*)(smem + 49152);
  float* g1s  = (float*)(smem + 49408);
  float* g2s  = (float*)(smem + 49664);

  const int tid = threadIdx.x;
  const int lane = tid & 63;
  const int wave = tid >> 6;
  const int wr = wave >> 1, wc = wave & 1;

  if (tid < 64) {
    int tk = -1; float2 gg = make_float2(0.f, 0.f);
    if (start + tid < n) {
      tk = pairlist[b * CAP + start + tid];
      gg = ggbuf[tk];
    }
    toks[tid] = tk; g1s[tid] = gg.x; g2s[tid] = gg.y;
  }

  f32x4 acc[2][4];
#pragma unroll
  for (int m = 0; m < 2; ++m)
#pragma unroll
    for (int nn = 0; nn < 4; ++nn) acc[m][nn] = (f32x4){0.f, 0.f, 0.f, 0.f};

  const ushort* wdA = wdt + ((size_t)ea << 16);
  const ushort* wdB = wdt + ((size_t)eb << 16);

  for (int s = 0; s < CDIM / 64; ++s) {
    const int k0 = s * 64;
    __syncthreads();
#pragma unroll
    for (int i2 = 0; i2 < 2; ++i2) {   // As: 64 tok x 64 k
      const int sc = tid + i2 * 256;
      const int row = sc >> 3;
      const int c8 = (sc & 7) * 8;
      const int tk = toks[row];
      const int tkc = tk < 0 ? 0 : tk;
      const ushort8 v = *(const ushort8*)(xb + (size_t)tkc * CDIM + k0 + c8);
      *(ushort8*)&As[row * 64 + (c8 ^ ((row & 7) << 3))] = v;
    }
    {                                   // BsA/BsB: 64 r x 64 k each
      const int r = tid & 63;
      const int kq = (tid >> 6) * 16;
      const ushort* srcA = wdA + ((size_t)r << 10) + k0 + kq;
      const ushort8 a0 = *(const ushort8*)(srcA);
      const ushort8 a1 = *(const ushort8*)(srcA + 8);
      *(ushort8*)&BsA[r * 64 + ((kq + 0) ^ ((r & 7) << 3))] = a0;
      *(ushort8*)&BsA[r * 64 + ((kq + 8) ^ ((r & 7) << 3))] = a1;
      const ushort* srcB = wdB + ((size_t)r << 10) + k0 + kq;
      const ushort8 b0 = *(const ushort8*)(srcB);
      const ushort8 b1 = *(const ushort8*)(srcB + 8);
      *(ushort8*)&BsB[r * 64 + ((kq + 0) ^ ((r & 7) << 3))] = b0;
      *(ushort8*)&BsB[r * 64 + ((kq + 8) ^ ((r & 7) << 3))] = b1;
    }
    __syncthreads();
    const ushort* Bsx = wc ? BsB : BsA;
#pragma unroll
    for (int kk = 0; kk < 64; kk += 32) {
      const int kb = kk + (lane >> 4) * 8;
      bf16x8 a[2], bb[4];
#pragma unroll
      for (int m = 0; m < 2; ++m) {
        const int row = wr * 32 + m * 16 + (lane & 15);
        a[m] = *(const bf16x8*)&As[row * 64 + (kb ^ ((row & 7) << 3))];
      }
#pragma unroll
      for (int nn = 0; nn < 4; ++nn) {
        const int r = nn * 16 + (lane & 15);
        bb[nn] = *(const bf16x8*)&Bsx[r * 64 + (kb ^ ((r & 7) << 3))];
      }
#pragma unroll
      for (int m = 0; m < 2; ++m)
#pragma unroll
        for (int nn = 0; nn < 4; ++nn)
          acc[m][nn] = __builtin_amdgcn_mfma_f32_16x16x32_bf16(a[m], bb[nn], acc[m][nn], 0, 0, 0);
    }
  }
  // phase-1 epilogue: GELU * gate -> Hs{wc} (swizzled)
  {
    ushort* Hsx = wc ? Hs1 : Hs0;
    const float* gsx = wc ? g2s : g1s;
#pragma unroll
    for (int m = 0; m < 2; ++m)
#pragma unroll
      for (int nn = 0; nn < 4; ++nn)
#pragma unroll
        for (int q = 0; q < 4; ++q) {
          const int slot = wr * 32 + m * 16 + (lane >> 4) * 4 + q;
          const int r = nn * 16 + (lane & 15);
          const float v = acc[m][nn][q];
          const float ge = 0.5f * v * (1.f + erff(v * 0.70710678118654752f));
          Hsx[slot * 64 + (r ^ ((slot & 7) << 3))] = f2bf(ge * gsx[slot]);
        }
  }
  __syncthreads();

  const ushort* wuA = wut + ((size_t)ea << 16);
  const ushort* wuB = wut + ((size_t)eb << 16);
#pragma unroll 1
  for (int n0 = 0; n0 < 8; ++n0) {
    {                                   // BuA/BuB: 128 c x 64 r each
      const int cc = tid & 127;
      const int rq = (tid >> 7) * 32;
      const ushort* sA = wuA + (((size_t)(n0 * 128 + cc)) << 6) + rq;
#pragma unroll
      for (int j = 0; j < 4; ++j)
        *(ushort8*)&BuA[cc * 64 + ((rq + 8 * j) ^ ((cc & 7) << 3))] =
            *(const ushort8*)(sA + 8 * j);
      const ushort* sB = wuB + (((size_t)(n0 * 128 + cc)) << 6) + rq;
#pragma unroll
      for (int j = 0; j < 4; ++j)
        *(ushort8*)&BuB[cc * 64 + ((rq + 8 * j) ^ ((cc & 7) << 3))] =
            *(const ushort8*)(sB + 8 * j);
    }
    __syncthreads();
    f32x4 uac[2][4];
#pragma unroll
    for (int m = 0; m < 2; ++m)
#pragma unroll
      for (int nn = 0; nn < 4; ++nn) uac[m][nn] = (f32x4){0.f, 0.f, 0.f, 0.f};
    // pass A: H0 @ WuA
#pragma unroll
    for (int kk = 0; kk < 64; kk += 32) {
      const int kb = kk + (lane >> 4) * 8;
      bf16x8 a[2], bb[4];
#pragma unroll
      for (int m = 0; m < 2; ++m) {
        const int row = wr * 32 + m * 16 + (lane & 15);
        a[m] = *(const bf16x8*)&Hs0[row * 64 + (kb ^ ((row & 7) << 3))];
      }
#pragma unroll
      for (int nn = 0; nn < 4; ++nn) {
        const int c = wc * 64 + nn * 16 + (lane & 15);
        bb[nn] = *(const bf16x8*)&BuA[c * 64 + (kb ^ ((c & 7) << 3))];
      }
#pragma unroll
      for (int m = 0; m < 2; ++m)
#pragma unroll
        for (int nn = 0; nn < 4; ++nn)
          uac[m][nn] = __builtin_amdgcn_mfma_f32_16x16x32_bf16(a[m], bb[nn], uac[m][nn], 0, 0, 0);
    }
    // pass B: H1 @ WuB (accumulate)
#pragma unroll
    for (int kk = 0; kk < 64; kk += 32) {
      const int kb = kk + (lane >> 4) * 8;
      bf16x8 a[2], bb[4];
#pragma unroll
      for (int m = 0; m < 2; ++m) {
        const int row = wr * 32 + m * 16 + (lane & 15);
        a[m] = *(const bf16x8*)&Hs1[row * 64 + (kb ^ ((row & 7) << 3))];
      }
#pragma unroll
      for (int nn = 0; nn < 4; ++nn) {
        const int c = wc * 64 + nn * 16 + (lane & 15);
        bb[nn] = *(const bf16x8*)&BuB[c * 64 + (kb ^ ((c & 7) << 3))];
      }
#pragma unroll
      for (int m = 0; m < 2; ++m)
#pragma unroll
        for (int nn = 0; nn < 4; ++nn)
          uac[m][nn] = __builtin_amdgcn_mfma_f32_16x16x32_bf16(a[m], bb[nn], uac[m][nn], 0, 0, 0);
    }
    // store this 128-col slice
#pragma unroll
    for (int m = 0; m < 2; ++m)
#pragma unroll
      for (int q = 0; q < 4; ++q) {
        const int slot = wr * 32 + m * 16 + (lane >> 4) * 4 + q;
        const int tk = toks[slot];
        if (tk >= 0) {
          float* orow = out + (size_t)tk * CDIM + n0 * 128 + wc * 64 + (lane & 15);
#pragma unroll
          for (int nn = 0; nn < 4; ++nn) orow[nn * 16] = uac[m][nn][q];
        }
      }
    __syncthreads();
  }
}

// ---------------- aux: deterministic reduce of per-block importance --------
__global__ __launch_bounds__(256) void aux_kernel(
    const int* __restrict__ cnt, const float* __restrict__ imp_part,
    float* __restrict__ out_aux) {
  __shared__ float red[256];
  __shared__ float tot[NEXP];
  const int t = threadIdx.x;
  const int e = t & 7, b0 = t >> 3;
  float s = 0.f;
  for (int j = 0; j < NBLK_R / 32; ++j)
    s += imp_part[(b0 + 32 * j) * 8 + e];
  red[t] = s;
  __syncthreads();
  if (t < 8) {
    float tt = 0.f;
    for (int w = 0; w < 32; ++w) tt += red[w * 8 + t];
    tot[t] = tt;
  }
  __syncthreads();
  if (t == 0) {
    float a = 0.f;
#pragma unroll
    for (int ee = 0; ee < NEXP; ++ee)
      a += (tot[ee] / (float)TOKS) *
           ((float)(cnt[ee * 32] + cnt[(NEXP + ee) * 32]) / (float)(2 * TOKS));
    out_aux[0] = 0.001f * 8.f * a;
  }
}

extern "C" void kernel_launch(void* const* d_in, const int* in_sizes, int n_in,
                              void* d_out, int out_size, void* d_ws, size_t ws_size,
                              hipStream_t stream) {
  const float* x   = (const float*)d_in[0];
  const float* rw  = (const float*)d_in[1];
  const float* rb  = (const float*)d_in[2];
  const float* Wd  = (const float*)d_in[3];
  const float* Wu  = (const float*)d_in[4];
  const int* key_id = (const int*)d_in[5];
  float* out = (float*)d_out;

  char* ws = (char*)d_ws;
  int*    cnt      = (int*)ws;                    // 2 KB  (16 x 128B)
  int*    cnt_pair = (int*)(ws + 2048);           // 8 KB  (64 x 128B)
  int*    totals   = (int*)(ws + 10240);          // 8 B
  float*  imp_part = (float*)(ws + 16384);        // 32 KB
  int*    fplan    = (int*)(ws + 49152);          // ~2 KB
  ushort* wdt      = (ushort*)(ws + 2162688);     // 1 MB
  ushort* wut      = (ushort*)(ws + 3211264);     // 1 MB
  ushort* xb       = (ushort*)(ws + 4259840);     // 32 MB -> 37814272
  float*  rw_p     = (float*)(ws + 37814272);     // 32 KB -> 37847040
  int*    pairlist = (int*)(ws + 37847040);       // 4 MB  -> 42041344
  // router scratch (consumed by scan/scatter before expert_kernel runs)
  int*    histT = (int*)(ws + 42041344);                // 320 KB
  int*    baseT = (int*)(ws + 42041344 + 327680);       // 320 KB
  int*    pbuf  = (int*)(ws + 42041344 + 655360);       // 64 KB
  float2* ggbuf = (float2*)(ws + 42041344 + 720896);    // 128 KB (live into expert)

  convert_kernel<<<1032, 256, 0, stream>>>(Wd, Wu, rw, key_id, wdt, wut, rw_p);
  router_kernel<<<NBLK_R, 256, 0, stream>>>(x, rw_p, rb, key_id, imp_part,
                                            pbuf, ggbuf, histT, xb);
  scan_kernel<<<80, 256, 0, stream>>>(histT, baseT, cnt, cnt_pair);
  scatter_kernel<<<257, 256, 0, stream>>>(baseT, pbuf, cnt_pair,
                                          pairlist, fplan, totals);
  expert_kernel<<<FT_MAX, 256, 0, stream>>>(xb, wdt, wut, cnt_pair, pairlist,
                                            ggbuf, fplan, totals, out);
  aux_kernel<<<1, 256, 0, stream>>>(cnt, imp_part, out + (size_t)TOKS * CDIM);
}

// Round 4
// 79.689 us; speedup vs baseline: 1.1801x; 1.1801x over previous
//
#include <hip/hip_runtime.h>
#include <hip/hip_bf16.h>
#include <math.h>

#define TOKS 16384
#define CDIM 1024
#define NEXP 8
#define RDIM 64
#define CAP  TOKS
#define NBLK_R 1024   // router blocks (16 tokens each)
#define FT_MAX 320    // max fused tiles: 16384/64 + 64 partials

using f32x4   = __attribute__((ext_vector_type(4))) float;
using bf16x8  = __attribute__((ext_vector_type(8))) short;
using ushort8 = __attribute__((ext_vector_type(8))) unsigned short;

__device__ __forceinline__ ushort f2bf(float f) {
  unsigned u = __builtin_bit_cast(unsigned, f);
  u += 0x7fffu + ((u >> 16) & 1u);   // round-to-nearest-even
  return (ushort)(u >> 16);
}

// ---- pre-pass: rw permute; Wd -> wdt[e][s][r][kk] (8KB tiles, s=k/64);
//      Wu -> wut[e][n0][cc][r] (16KB tiles, n0=c/128). Tile-contiguous so
//      expert_kernel staging is fully coalesced.
__global__ __launch_bounds__(256) void convert_kernel(
    const float* __restrict__ Wd, const float* __restrict__ Wu,
    const float* __restrict__ rw_all, const int* __restrict__ key_id,
    ushort* __restrict__ wdt, ushort* __restrict__ wut,
    float* __restrict__ rw_p) {
  const int t = blockIdx.x * 256 + threadIdx.x;
  if (t < 2048) {              // rw_p: one float4 per thread
    const int st = t >> 7, rem = t & 127;
    const int h = rem >> 6, l = rem & 63;
    const int C = (st >> 2) * 256 + l * 4 + (st & 3);
    const float4 v = *(const float4*)(rw_all + (size_t)key_id[0] * CDIM * NEXP
                                      + C * 8 + h * 4);
    ((float4*)rw_p)[t] = v;
  } else if (t < 133120) {     // Wd: (e, r, k4) -> wdt[((e*16+s)*64+r)*16 + kq4]
    const int u = t - 2048;
    const int k4 = u & 255, r = (u >> 8) & 63, e = u >> 14;
    ushort4 h;
    h.x = f2bf(Wd[(size_t)(e * 1024 + k4 * 4 + 0) * 64 + r]);
    h.y = f2bf(Wd[(size_t)(e * 1024 + k4 * 4 + 1) * 64 + r]);
    h.z = f2bf(Wd[(size_t)(e * 1024 + k4 * 4 + 2) * 64 + r]);
    h.w = f2bf(Wd[(size_t)(e * 1024 + k4 * 4 + 3) * 64 + r]);
    const int s = k4 >> 4;          // k-block
    const int kq4 = k4 & 15;        // ushort4 index within row
    ((ushort4*)wdt)[((e * 16 + s) * 64 + r) * 16 + kq4] = h;
  } else {                     // Wu: (e, c, r4) -> wut[((e*8+n0)*128+cc)*16 + r4]
    const int u = t - 133120;
    const int r4 = u & 15, c = (u >> 4) & 1023, e = u >> 14;
    ushort4 h;
    h.x = f2bf(Wu[(size_t)(e * 64 + r4 * 4 + 0) * 1024 + c]);
    h.y = f2bf(Wu[(size_t)(e * 64 + r4 * 4 + 1) * 1024 + c]);
    h.z = f2bf(Wu[(size_t)(e * 64 + r4 * 4 + 2) * 1024 + c]);
    h.w = f2bf(Wu[(size_t)(e * 64 + r4 * 4 + 3) * 1024 + c]);
    const int n0 = c >> 7, cc = c & 127;
    ((ushort4*)wut)[((e * 8 + n0) * 128 + cc) * 16 + r4] = h;
  }
}

// ---------------- router: wave = token; NO global atomics ------------------
__global__ __launch_bounds__(256) void router_kernel(
    const float* __restrict__ x, const float* __restrict__ rw_p,
    const float* __restrict__ rb_all, const int* __restrict__ key_id,
    float* __restrict__ imp_part,
    int* __restrict__ pbuf, float2* __restrict__ ggbuf,
    int* __restrict__ histT, ushort* __restrict__ xb) {
  __shared__ float s_imp[4][NEXP];
  __shared__ int   s_pb[16];
  __shared__ float s_g1[16], s_g2[16];
  const int tid = threadIdx.x;
  const int lane = tid & 63;
  const int wave = tid >> 6;
  const int kid = key_id[0];
  const float4* rwp4 = (const float4*)rw_p;
  const float* rb = rb_all + (size_t)kid * NEXP;
  const int eln = ((lane & 1) << 2) | (lane & 2) | ((lane >> 2) & 1);
  const float rbe = rb[eln];
  float impacc = 0.f;

  const int wg = blockIdx.x * 4 + wave;
#pragma unroll 1
  for (int tt = 0; tt < 4; ++tt) {
    const int token = wg * 4 + tt;
    const float* xr = x + (size_t)token * CDIM + lane * 4;
    float4 xv[4];
#pragma unroll
    for (int j = 0; j < 4; ++j) xv[j] = *(const float4*)(xr + j * 256);
    ushort* xo = xb + (size_t)token * CDIM + lane * 4;
#pragma unroll
    for (int j = 0; j < 4; ++j) {
      ushort4 h;
      h.x = f2bf(xv[j].x); h.y = f2bf(xv[j].y);
      h.z = f2bf(xv[j].z); h.w = f2bf(xv[j].w);
      *(ushort4*)(xo + j * 256) = h;
    }
    float acc[8];
#pragma unroll
    for (int e = 0; e < 8; ++e) acc[e] = 0.f;
#pragma unroll
    for (int j = 0; j < 4; ++j) {
#pragma unroll
      for (int i = 0; i < 4; ++i) {
        const int st = j * 4 + i;
        const float4 wA = rwp4[st * 128 + lane];
        const float4 wB = rwp4[st * 128 + 64 + lane];
        const float xi = (&xv[j].x)[i];
        acc[0] = fmaf(xi, wA.x, acc[0]);
        acc[1] = fmaf(xi, wA.y, acc[1]);
        acc[2] = fmaf(xi, wA.z, acc[2]);
        acc[3] = fmaf(xi, wA.w, acc[3]);
        acc[4] = fmaf(xi, wB.x, acc[4]);
        acc[5] = fmaf(xi, wB.y, acc[5]);
        acc[6] = fmaf(xi, wB.z, acc[6]);
        acc[7] = fmaf(xi, wB.w, acc[7]);
      }
    }
    // butterfly 8 accs -> 1 (expert = bitrev3(lane&7)), then 64-lane sum
#pragma unroll
    for (int i = 0; i < 4; ++i) {
      const float send = (lane & 1) ? acc[i] : acc[i + 4];
      const float recv = __shfl_xor(send, 1);
      acc[i] = ((lane & 1) ? acc[i + 4] : acc[i]) + recv;
    }
#pragma unroll
    for (int i = 0; i < 2; ++i) {
      const float send = (lane & 2) ? acc[i] : acc[i + 2];
      const float recv = __shfl_xor(send, 2);
      acc[i] = ((lane & 2) ? acc[i + 2] : acc[i]) + recv;
    }
    {
      const float send = (lane & 4) ? acc[0] : acc[1];
      const float recv = __shfl_xor(send, 4);
      acc[0] = ((lane & 4) ? acc[1] : acc[0]) + recv;
    }
    float v = acc[0];
    v += __shfl_xor(v, 8); v += __shfl_xor(v, 16); v += __shfl_xor(v, 32);

    const float logit = v + rbe;
    float mx = logit;
    mx = fmaxf(mx, __shfl_xor(mx, 1));
    mx = fmaxf(mx, __shfl_xor(mx, 2));
    mx = fmaxf(mx, __shfl_xor(mx, 4));
    const float ex = expf(logit - mx);
    float sm = ex;
    sm += __shfl_xor(sm, 1); sm += __shfl_xor(sm, 2); sm += __shfl_xor(sm, 4);
    const float p = ex / sm;
    float bv = p; int bi = eln;
#pragma unroll
    for (int mk = 1; mk <= 4; mk <<= 1) {
      const float ov = __shfl_xor(bv, mk);
      const int oi = __shfl_xor(bi, mk);
      if (ov > bv || (ov == bv && oi < bi)) { bv = ov; bi = oi; }
    }
    const int e1 = bi; const float v1 = bv;
    float cv = (eln == e1) ? -1.f : p; int ci = eln;
#pragma unroll
    for (int mk = 1; mk <= 4; mk <<= 1) {
      const float ov = __shfl_xor(cv, mk);
      const int oi = __shfl_xor(ci, mk);
      if (ov > cv || (ov == cv && oi < ci)) { cv = ov; ci = oi; }
    }
    const int e2 = ci; const float v2 = cv;

    if (lane == 0) {
      const float gs = 1.f / (v1 + v2);
      const int li = wave * 4 + tt;
      s_g1[li] = v1 * gs;
      s_g2[li] = v2 * gs;
      s_pb[li] = e1 * 8 + e2;
    }
    impacc += p;
  }
  if (lane < 8) s_imp[wave][eln] = impacc;
  __syncthreads();
  if (tid < 8)
    imp_part[blockIdx.x * 8 + tid] =
        s_imp[0][tid] + s_imp[1][tid] + s_imp[2][tid] + s_imp[3][tid];

  // per-token records (coalesced, block-contiguous)
  if (tid < 16) {
    pbuf[blockIdx.x * 16 + tid] = s_pb[tid];
    ggbuf[blockIdx.x * 16 + tid] = make_float2(s_g1[tid], s_g2[tid]);
  }
  // transposed histograms: histT[c*1024 + blk], c in [0,80)
  if (tid < 80) {
    int c = 0;
    if (tid < 16) {
      const int k = tid >> 3, e = tid & 7;
#pragma unroll
      for (int j = 0; j < 16; ++j)
        c += ((k ? (s_pb[j] & 7) : (s_pb[j] >> 3)) == e) ? 1 : 0;
    } else {
      const int b = tid - 16;
#pragma unroll
      for (int j = 0; j < 16; ++j) c += (s_pb[j] == b) ? 1 : 0;
    }
    histT[tid * 1024 + blockIdx.x] = c;
  }
}

// -------- scan: one block per counter, parallel prefix over 1024 blocks ----
__global__ __launch_bounds__(256) void scan_kernel(
    const int* __restrict__ histT, int* __restrict__ baseT,
    int* __restrict__ cnt, int* __restrict__ cnt_pair) {
  __shared__ int ls[256];
  const int c = blockIdx.x;
  const int t = threadIdx.x;
  const int4 v = ((const int4*)(histT + (c << 10)))[t];
  const int s = v.x + v.y + v.z + v.w;
  ls[t] = s;
  __syncthreads();
#pragma unroll
  for (int off = 1; off < 256; off <<= 1) {
    const int add = (t >= off) ? ls[t - off] : 0;
    __syncthreads();
    ls[t] += add;
    __syncthreads();
  }
  const int incl = ls[t];
  const int excl = incl - s;
  int4 b;
  b.x = excl;
  b.y = excl + v.x;
  b.z = excl + v.x + v.y;
  b.w = excl + v.x + v.y + v.z;
  ((int4*)(baseT + (c << 10)))[t] = b;
  if (t == 255) {
    if (c < 16) cnt[c * 32] = incl;
    else        cnt_pair[(c - 16) * 32] = incl;
  }
}

// -------- scatter (blocks 0..255) + plan (block 256) -----------------------
__global__ __launch_bounds__(256) void scatter_kernel(
    const int* __restrict__ baseT, const int* __restrict__ pbuf,
    const int* __restrict__ cnt_pair,
    int* __restrict__ pairlist, int* __restrict__ fplan,
    int* __restrict__ totals) {
  if (blockIdx.x == 256) {   // plan: 64-token tiles per pair bucket
    __shared__ int uoff[64];
    const int t = threadIdx.x;
    if (t == 0) {
      int a = 0;
      for (int b = 0; b < 64; ++b) { uoff[b] = a; a += (cnt_pair[b * 32] + 63) >> 6; }
      totals[1] = a;
    }
    __syncthreads();
    if (t < 64) {
      const int nb = (cnt_pair[t * 32] + 63) >> 6;
      for (int i = 0; i < nb; ++i) fplan[uoff[t] + i] = (t << 16) | i;
    }
    return;
  }
  const int tid = threadIdx.x;
  const int lane = tid & 63;
  const int wave = tid >> 6;
  const int rb = blockIdx.x * 4 + wave;   // router block, 0..1023
  const int i = lane;
  int pb = 0;
  if (lane < 16) pb = pbuf[rb * 16 + lane];
  int rp = 0;
#pragma unroll
  for (int j = 0; j < 15; ++j) {
    const int q = __shfl(pb, j);
    if (j < i) rp += (q == pb) ? 1 : 0;
  }
  if (lane < 16) {
    const int token = rb * 16 + i;
    const int sp = baseT[((16 + pb) << 10) + rb] + rp;
    pairlist[pb * CAP + sp] = token;
  }
}

// ---- fused expert: per 64-token pair tile, down(GELU,gate) -> up -> out ----
// Phase 1: H0|H1 = GELU(x@Wd_e1)*g1 | GELU(x@Wd_e2)*g2   (M=64, N=128, K=1024)
//   coalesced Wd tiles + register prefetch of step s+1 under MFMA of step s.
// Phase 2: for 8 col slices: out = H0@WuA + H1@WuB        (M=64, N=128, K=64+64)
//   coalesced Wu tiles + register prefetch of slice n0+1 under MFMA of n0.
__global__ __launch_bounds__(256) void expert_kernel(
    const ushort* __restrict__ xb, const ushort* __restrict__ wdt,
    const ushort* __restrict__ wut,
    const int* __restrict__ cnt_pair, const int* __restrict__ pairlist,
    const float2* __restrict__ ggbuf,
    const int* __restrict__ fplan, const int* __restrict__ totals,
    float* __restrict__ out) {
  if (blockIdx.x >= totals[1]) return;
  const int ent = fplan[blockIdx.x];
  const int b = ent >> 16, tile = ent & 0xffff;
  const int ea = b >> 3, eb = b & 7;
  const int n = cnt_pair[b * 32];
  const int start = tile * 64;

  __shared__ __align__(16) char smem[50176];
  ushort* As  = (ushort*)(smem);            // 8 KB  phase1 (aliased by BuA)
  ushort* BsA = (ushort*)(smem + 8192);     // 8 KB  phase1
  ushort* BsB = (ushort*)(smem + 16384);    // 8 KB  phase1
  ushort* BuA = (ushort*)(smem);            // 16 KB phase2
  ushort* BuB = (ushort*)(smem + 16384);    // 16 KB phase2
  ushort* Hs0 = (ushort*)(smem + 32768);    // 8 KB
  ushort* Hs1 = (ushort*)(smem + 40960);    // 8 KB
  int*   toks = (int*)(smem + 49152);
  float* g1s  = (float*)(smem + 49408);
  float* g2s  = (float*)(smem + 49664);

  const int tid = threadIdx.x;
  const int lane = tid & 63;
  const int wave = tid >> 6;
  const int wr = wave >> 1, wc = wave & 1;

  if (tid < 64) {
    int tk = -1; float2 gg = make_float2(0.f, 0.f);
    if (start + tid < n) {
      tk = pairlist[b * CAP + start + tid];
      gg = ggbuf[tk];
    }
    toks[tid] = tk; g1s[tid] = gg.x; g2s[tid] = gg.y;
  }
  __syncthreads();

  // staging geometry (shared by As/BsA/BsB: 64x64 tiles, linear bytes)
  const int rowS0 = tid >> 3;           // 0..31
  const int rowS1 = 32 + rowS0;         // 32..63
  const int c8s = (tid & 7) * 8;
  const int swzS = (rowS0 & 7) << 3;    // same for rowS1
  const int lofA0 = rowS0 * 64 + (c8s ^ swzS);
  const int lofA1 = rowS1 * 64 + (c8s ^ swzS);

  const int tk0 = toks[rowS0], tk1 = toks[rowS1];
  const ushort* xrow0 = xb + (size_t)(tk0 < 0 ? 0 : tk0) * CDIM + c8s;
  const ushort* xrow1 = xb + (size_t)(tk1 < 0 ? 0 : tk1) * CDIM + c8s;
  const ushort* wdA = wdt + ((size_t)ea << 16);   // 16 tiles x 4096
  const ushort* wdB = wdt + ((size_t)eb << 16);

  f32x4 acc[2][4];
#pragma unroll
  for (int m = 0; m < 2; ++m)
#pragma unroll
    for (int nn = 0; nn < 4; ++nn) acc[m][nn] = (f32x4){0.f, 0.f, 0.f, 0.f};

  ushort8 rA0, rA1, rBA0, rBA1, rBB0, rBB1;
  // prologue: load step 0
  {
    rA0  = *(const ushort8*)(xrow0);
    rA1  = *(const ushort8*)(xrow1);
    rBA0 = *(const ushort8*)(wdA + tid * 8);
    rBA1 = *(const ushort8*)(wdA + (tid + 256) * 8);
    rBB0 = *(const ushort8*)(wdB + tid * 8);
    rBB1 = *(const ushort8*)(wdB + (tid + 256) * 8);
  }

#pragma unroll 1
  for (int s = 0; s < 16; ++s) {
    __syncthreads();                       // LDS free (prev MFMA done)
    *(ushort8*)&As [lofA0] = rA0;
    *(ushort8*)&As [lofA1] = rA1;
    *(ushort8*)&BsA[lofA0] = rBA0;
    *(ushort8*)&BsA[lofA1] = rBA1;
    *(ushort8*)&BsB[lofA0] = rBB0;
    *(ushort8*)&BsB[lofA1] = rBB1;
    if (s < 15) {                          // prefetch step s+1 (overlaps MFMA)
      const int k1 = (s + 1) * 64;
      rA0  = *(const ushort8*)(xrow0 + k1);
      rA1  = *(const ushort8*)(xrow1 + k1);
      rBA0 = *(const ushort8*)(wdA + ((s + 1) << 12) + tid * 8);
      rBA1 = *(const ushort8*)(wdA + ((s + 1) << 12) + (tid + 256) * 8);
      rBB0 = *(const ushort8*)(wdB + ((s + 1) << 12) + tid * 8);
      rBB1 = *(const ushort8*)(wdB + ((s + 1) << 12) + (tid + 256) * 8);
    }
    __syncthreads();
    const ushort* Bsx = wc ? BsB : BsA;
#pragma unroll
    for (int kk = 0; kk < 64; kk += 32) {
      const int kb = kk + (lane >> 4) * 8;
      bf16x8 a[2], bb[4];
#pragma unroll
      for (int m = 0; m < 2; ++m) {
        const int row = wr * 32 + m * 16 + (lane & 15);
        a[m] = *(const bf16x8*)&As[row * 64 + (kb ^ ((row & 7) << 3))];
      }
#pragma unroll
      for (int nn = 0; nn < 4; ++nn) {
        const int r = nn * 16 + (lane & 15);
        bb[nn] = *(const bf16x8*)&Bsx[r * 64 + (kb ^ ((r & 7) << 3))];
      }
#pragma unroll
      for (int m = 0; m < 2; ++m)
#pragma unroll
        for (int nn = 0; nn < 4; ++nn)
          acc[m][nn] = __builtin_amdgcn_mfma_f32_16x16x32_bf16(a[m], bb[nn], acc[m][nn], 0, 0, 0);
    }
  }

  // issue phase-2 slice-0 weight loads early (hide under GELU epilogue)
  const ushort* wuA = wut + ((size_t)ea << 16);   // 8 tiles x 8192
  const ushort* wuB = wut + ((size_t)eb << 16);
  ushort8 rUA[4], rUB[4];
#pragma unroll
  for (int j = 0; j < 4; ++j) {
    rUA[j] = *(const ushort8*)(wuA + (tid + j * 256) * 8);
    rUB[j] = *(const ushort8*)(wuB + (tid + j * 256) * 8);
  }

  // phase-1 epilogue: GELU * gate -> Hs{wc} (swizzled)
  {
    ushort* Hsx = wc ? Hs1 : Hs0;
    const float* gsx = wc ? g2s : g1s;
#pragma unroll
    for (int m = 0; m < 2; ++m)
#pragma unroll
      for (int nn = 0; nn < 4; ++nn)
#pragma unroll
        for (int q = 0; q < 4; ++q) {
          const int slot = wr * 32 + m * 16 + (lane >> 4) * 4 + q;
          const int r = nn * 16 + (lane & 15);
          const float v = acc[m][nn][q];
          const float ge = 0.5f * v * (1.f + erff(v * 0.70710678118654752f));
          Hsx[slot * 64 + (r ^ ((slot & 7) << 3))] = f2bf(ge * gsx[slot]);
        }
  }

  // phase-2 staging geometry (128x64 tiles)
  const int ccS0 = tid >> 3;            // j: cc = ccS0 + j*32
  const int rq8 = (tid & 7) * 8;
  const int swzU = (ccS0 & 7) << 3;     // same for all j (cc + 32j keeps &7)

#pragma unroll 1
  for (int n0 = 0; n0 < 8; ++n0) {
    __syncthreads();                     // Hs done / prev MFMA done reading Bu
#pragma unroll
    for (int j = 0; j < 4; ++j) {
      const int cc = ccS0 + j * 32;
      *(ushort8*)&BuA[cc * 64 + (rq8 ^ swzU)] = rUA[j];
      *(ushort8*)&BuB[cc * 64 + (rq8 ^ swzU)] = rUB[j];
    }
    if (n0 < 7) {                        // prefetch next slice
#pragma unroll
      for (int j = 0; j < 4; ++j) {
        rUA[j] = *(const ushort8*)(wuA + ((n0 + 1) << 13) + (tid + j * 256) * 8);
        rUB[j] = *(const ushort8*)(wuB + ((n0 + 1) << 13) + (tid + j * 256) * 8);
      }
    }
    __syncthreads();
    f32x4 uac[2][4];
#pragma unroll
    for (int m = 0; m < 2; ++m)
#pragma unroll
      for (int nn = 0; nn < 4; ++nn) uac[m][nn] = (f32x4){0.f, 0.f, 0.f, 0.f};
    // pass A: H0 @ WuA
#pragma unroll
    for (int kk = 0; kk < 64; kk += 32) {
      const int kb = kk + (lane >> 4) * 8;
      bf16x8 a[2], bb[4];
#pragma unroll
      for (int m = 0; m < 2; ++m) {
        const int row = wr * 32 + m * 16 + (lane & 15);
        a[m] = *(const bf16x8*)&Hs0[row * 64 + (kb ^ ((row & 7) << 3))];
      }
#pragma unroll
      for (int nn = 0; nn < 4; ++nn) {
        const int c = wc * 64 + nn * 16 + (lane & 15);
        bb[nn] = *(const bf16x8*)&BuA[c * 64 + (kb ^ ((c & 7) << 3))];
      }
#pragma unroll
      for (int m = 0; m < 2; ++m)
#pragma unroll
        for (int nn = 0; nn < 4; ++nn)
          uac[m][nn] = __builtin_amdgcn_mfma_f32_16x16x32_bf16(a[m], bb[nn], uac[m][nn], 0, 0, 0);
    }
    // pass B: H1 @ WuB (accumulate)
#pragma unroll
    for (int kk = 0; kk < 64; kk += 32) {
      const int kb = kk + (lane >> 4) * 8;
      bf16x8 a[2], bb[4];
#pragma unroll
      for (int m = 0; m < 2; ++m) {
        const int row = wr * 32 + m * 16 + (lane & 15);
        a[m] = *(const bf16x8*)&Hs1[row * 64 + (kb ^ ((row & 7) << 3))];
      }
#pragma unroll
      for (int nn = 0; nn < 4; ++nn) {
        const int c = wc * 64 + nn * 16 + (lane & 15);
        bb[nn] = *(const bf16x8*)&BuB[c * 64 + (kb ^ ((c & 7) << 3))];
      }
#pragma unroll
      for (int m = 0; m < 2; ++m)
#pragma unroll
        for (int nn = 0; nn < 4; ++nn)
          uac[m][nn] = __builtin_amdgcn_mfma_f32_16x16x32_bf16(a[m], bb[nn], uac[m][nn], 0, 0, 0);
    }
    // store this 128-col slice
#pragma unroll
    for (int m = 0; m < 2; ++m)
#pragma unroll
      for (int q = 0; q < 4; ++q) {
        const int slot = wr * 32 + m * 16 + (lane >> 4) * 4 + q;
        const int tk = toks[slot];
        if (tk >= 0) {
          float* orow = out + (size_t)tk * CDIM + n0 * 128 + wc * 64 + (lane & 15);
#pragma unroll
          for (int nn = 0; nn < 4; ++nn) orow[nn * 16] = uac[m][nn][q];
        }
      }
  }
}

// ---------------- aux: deterministic reduce of per-block importance --------
__global__ __launch_bounds__(256) void aux_kernel(
    const int* __restrict__ cnt, const float* __restrict__ imp_part,
    float* __restrict__ out_aux) {
  __shared__ float red[256];
  __shared__ float tot[NEXP];
  const int t = threadIdx.x;
  const int e = t & 7, b0 = t >> 3;
  float s = 0.f;
  for (int j = 0; j < NBLK_R / 32; ++j)
    s += imp_part[(b0 + 32 * j) * 8 + e];
  red[t] = s;
  __syncthreads();
  if (t < 8) {
    float tt = 0.f;
    for (int w = 0; w < 32; ++w) tt += red[w * 8 + t];
    tot[t] = tt;
  }
  __syncthreads();
  if (t == 0) {
    float a = 0.f;
#pragma unroll
    for (int ee = 0; ee < NEXP; ++ee)
      a += (tot[ee] / (float)TOKS) *
           ((float)(cnt[ee * 32] + cnt[(NEXP + ee) * 32]) / (float)(2 * TOKS));
    out_aux[0] = 0.001f * 8.f * a;
  }
}

extern "C" void kernel_launch(void* const* d_in, const int* in_sizes, int n_in,
                              void* d_out, int out_size, void* d_ws, size_t ws_size,
                              hipStream_t stream) {
  const float* x   = (const float*)d_in[0];
  const float* rw  = (const float*)d_in[1];
  const float* rb  = (const float*)d_in[2];
  const float* Wd  = (const float*)d_in[3];
  const float* Wu  = (const float*)d_in[4];
  const int* key_id = (const int*)d_in[5];
  float* out = (float*)d_out;

  char* ws = (char*)d_ws;
  int*    cnt      = (int*)ws;                    // 2 KB  (16 x 128B)
  int*    cnt_pair = (int*)(ws + 2048);           // 8 KB  (64 x 128B)
  int*    totals   = (int*)(ws + 10240);          // 8 B
  float*  imp_part = (float*)(ws + 16384);        // 32 KB
  int*    fplan    = (int*)(ws + 49152);          // ~2 KB
  ushort* wdt      = (ushort*)(ws + 2162688);     // 1 MB
  ushort* wut      = (ushort*)(ws + 3211264);     // 1 MB
  ushort* xb       = (ushort*)(ws + 4259840);     // 32 MB -> 37814272
  float*  rw_p     = (float*)(ws + 37814272);     // 32 KB -> 37847040
  int*    pairlist = (int*)(ws + 37847040);       // 4 MB  -> 42041344
  // router scratch (consumed by scan/scatter before expert_kernel runs)
  int*    histT = (int*)(ws + 42041344);                // 320 KB
  int*    baseT = (int*)(ws + 42041344 + 327680);       // 320 KB
  int*    pbuf  = (int*)(ws + 42041344 + 655360);       // 64 KB
  float2* ggbuf = (float2*)(ws + 42041344 + 720896);    // 128 KB (live into expert)

  convert_kernel<<<1032, 256, 0, stream>>>(Wd, Wu, rw, key_id, wdt, wut, rw_p);
  router_kernel<<<NBLK_R, 256, 0, stream>>>(x, rw_p, rb, key_id, imp_part,
                                            pbuf, ggbuf, histT, xb);
  scan_kernel<<<80, 256, 0, stream>>>(histT, baseT, cnt, cnt_pair);
  scatter_kernel<<<257, 256, 0, stream>>>(baseT, pbuf, cnt_pair,
                                          pairlist, fplan, totals);
  expert_kernel<<<FT_MAX, 256, 0, stream>>>(xb, wdt, wut, cnt_pair, pairlist,
                                            ggbuf, fplan, totals, out);
  aux_kernel<<<1, 256, 0, stream>>>(cnt, imp_part, out + (size_t)TOKS * CDIM);
}

// Round 5
// 79.505 us; speedup vs baseline: 1.1829x; 1.0023x over previous
//
#include <hip/hip_runtime.h>
#include <hip/hip_bf16.h>
#include <math.h>

#define TOKS 16384
#define CDIM 1024
#define NEXP 8
#define RDIM 64
#define CAP  TOKS
#define NBLK_R 1024   // router blocks (16 tokens each)
#define FT_MAX 320    // max fused tiles: 16384/64 + 64 partials
#define NSPLIT 2      // output-slice split (blockIdx.y)

using f32x4   = __attribute__((ext_vector_type(4))) float;
using bf16x8  = __attribute__((ext_vector_type(8))) short;
using ushort8 = __attribute__((ext_vector_type(8))) unsigned short;

__device__ __forceinline__ ushort f2bf(float f) {
  unsigned u = __builtin_bit_cast(unsigned, f);
  u += 0x7fffu + ((u >> 16) & 1u);   // round-to-nearest-even
  return (ushort)(u >> 16);
}

// async global->LDS DMA, 16B per lane; lds dest is wave-uniform base,
// HW scatters lane l -> base + l*16.
__device__ __forceinline__ void async16(const ushort* g, ushort* l) {
  __builtin_amdgcn_global_load_lds(
      (const __attribute__((address_space(1))) void*)g,
      (__attribute__((address_space(3))) void*)l, 16, 0, 0);
}

// ---- pre-pass: rw permute; Wd -> wdt[e][s][r][k] tiles PRE-SWIZZLED so a
//      linear global_load_lds DMA lands in the XOR-swizzled LDS layout;
//      Wu -> wut[e][n0][cc][r] tiles, same pre-swizzle.
__global__ __launch_bounds__(256) void convert_kernel(
    const float* __restrict__ Wd, const float* __restrict__ Wu,
    const float* __restrict__ rw_all, const int* __restrict__ key_id,
    ushort* __restrict__ wdt, ushort* __restrict__ wut,
    float* __restrict__ rw_p) {
  const int t = blockIdx.x * 256 + threadIdx.x;
  if (t < 2048) {              // rw_p: one float4 per thread
    const int st = t >> 7, rem = t & 127;
    const int h = rem >> 6, l = rem & 63;
    const int C = (st >> 2) * 256 + l * 4 + (st & 3);
    const float4 v = *(const float4*)(rw_all + (size_t)key_id[0] * CDIM * NEXP
                                      + C * 8 + h * 4);
    ((float4*)rw_p)[t] = v;
  } else if (t < 133120) {     // Wd -> tile (e,s): [64 r][64 k], swizzled
    const int u = t - 2048;
    const int k4 = u & 255, r = (u >> 8) & 63, e = u >> 14;
    ushort4 h4;
    h4.x = f2bf(Wd[(size_t)(e * 1024 + k4 * 4 + 0) * 64 + r]);
    h4.y = f2bf(Wd[(size_t)(e * 1024 + k4 * 4 + 1) * 64 + r]);
    h4.z = f2bf(Wd[(size_t)(e * 1024 + k4 * 4 + 2) * 64 + r]);
    h4.w = f2bf(Wd[(size_t)(e * 1024 + k4 * 4 + 3) * 64 + r]);
    const int s = k4 >> 4;           // k-block (64-wide)
    const int kq4 = k4 & 15;         // ushort4 granule within row
    const int g = kq4 >> 1, hh = kq4 & 1;
    const int gs = g ^ (r & 7);      // pre-swizzle 8-ushort granule
    ((ushort4*)wdt)[((e * 16 + s) * 64 + r) * 16 + gs * 2 + hh] = h4;
  } else {                     // Wu -> tile (e,n0): [128 c][64 r], swizzled
    const int u = t - 133120;
    const int r4 = u & 15, c = (u >> 4) & 1023, e = u >> 14;
    ushort4 h4;
    h4.x = f2bf(Wu[(size_t)(e * 64 + r4 * 4 + 0) * 1024 + c]);
    h4.y = f2bf(Wu[(size_t)(e * 64 + r4 * 4 + 1) * 1024 + c]);
    h4.z = f2bf(Wu[(size_t)(e * 64 + r4 * 4 + 2) * 1024 + c]);
    h4.w = f2bf(Wu[(size_t)(e * 64 + r4 * 4 + 3) * 1024 + c]);
    const int n0 = c >> 7, cc = c & 127;
    const int g = r4 >> 1, hh = r4 & 1;
    const int gs = g ^ (cc & 7);
    ((ushort4*)wut)[((e * 8 + n0) * 128 + cc) * 16 + gs * 2 + hh] = h4;
  }
}

// ---------------- router: wave = token; NO global atomics ------------------
__global__ __launch_bounds__(256) void router_kernel(
    const float* __restrict__ x, const float* __restrict__ rw_p,
    const float* __restrict__ rb_all, const int* __restrict__ key_id,
    float* __restrict__ imp_part,
    int* __restrict__ pbuf, float2* __restrict__ ggbuf,
    int* __restrict__ histT, ushort* __restrict__ xb) {
  __shared__ float s_imp[4][NEXP];
  __shared__ int   s_pb[16];
  __shared__ float s_g1[16], s_g2[16];
  const int tid = threadIdx.x;
  const int lane = tid & 63;
  const int wave = tid >> 6;
  const int kid = key_id[0];
  const float4* rwp4 = (const float4*)rw_p;
  const float* rb = rb_all + (size_t)kid * NEXP;
  const int eln = ((lane & 1) << 2) | (lane & 2) | ((lane >> 2) & 1);
  const float rbe = rb[eln];
  float impacc = 0.f;

  const int wg = blockIdx.x * 4 + wave;
#pragma unroll 1
  for (int tt = 0; tt < 4; ++tt) {
    const int token = wg * 4 + tt;
    const float* xr = x + (size_t)token * CDIM + lane * 4;
    float4 xv[4];
#pragma unroll
    for (int j = 0; j < 4; ++j) xv[j] = *(const float4*)(xr + j * 256);
    ushort* xo = xb + (size_t)token * CDIM + lane * 4;
#pragma unroll
    for (int j = 0; j < 4; ++j) {
      ushort4 h;
      h.x = f2bf(xv[j].x); h.y = f2bf(xv[j].y);
      h.z = f2bf(xv[j].z); h.w = f2bf(xv[j].w);
      *(ushort4*)(xo + j * 256) = h;
    }
    float acc[8];
#pragma unroll
    for (int e = 0; e < 8; ++e) acc[e] = 0.f;
#pragma unroll
    for (int j = 0; j < 4; ++j) {
#pragma unroll
      for (int i = 0; i < 4; ++i) {
        const int st = j * 4 + i;
        const float4 wA = rwp4[st * 128 + lane];
        const float4 wB = rwp4[st * 128 + 64 + lane];
        const float xi = (&xv[j].x)[i];
        acc[0] = fmaf(xi, wA.x, acc[0]);
        acc[1] = fmaf(xi, wA.y, acc[1]);
        acc[2] = fmaf(xi, wA.z, acc[2]);
        acc[3] = fmaf(xi, wA.w, acc[3]);
        acc[4] = fmaf(xi, wB.x, acc[4]);
        acc[5] = fmaf(xi, wB.y, acc[5]);
        acc[6] = fmaf(xi, wB.z, acc[6]);
        acc[7] = fmaf(xi, wB.w, acc[7]);
      }
    }
    // butterfly 8 accs -> 1 (expert = bitrev3(lane&7)), then 64-lane sum
#pragma unroll
    for (int i = 0; i < 4; ++i) {
      const float send = (lane & 1) ? acc[i] : acc[i + 4];
      const float recv = __shfl_xor(send, 1);
      acc[i] = ((lane & 1) ? acc[i + 4] : acc[i]) + recv;
    }
#pragma unroll
    for (int i = 0; i < 2; ++i) {
      const float send = (lane & 2) ? acc[i] : acc[i + 2];
      const float recv = __shfl_xor(send, 2);
      acc[i] = ((lane & 2) ? acc[i + 2] : acc[i]) + recv;
    }
    {
      const float send = (lane & 4) ? acc[0] : acc[1];
      const float recv = __shfl_xor(send, 4);
      acc[0] = ((lane & 4) ? acc[1] : acc[0]) + recv;
    }
    float v = acc[0];
    v += __shfl_xor(v, 8); v += __shfl_xor(v, 16); v += __shfl_xor(v, 32);

    const float logit = v + rbe;
    float mx = logit;
    mx = fmaxf(mx, __shfl_xor(mx, 1));
    mx = fmaxf(mx, __shfl_xor(mx, 2));
    mx = fmaxf(mx, __shfl_xor(mx, 4));
    const float ex = expf(logit - mx);
    float sm = ex;
    sm += __shfl_xor(sm, 1); sm += __shfl_xor(sm, 2); sm += __shfl_xor(sm, 4);
    const float p = ex / sm;
    float bv = p; int bi = eln;
#pragma unroll
    for (int mk = 1; mk <= 4; mk <<= 1) {
      const float ov = __shfl_xor(bv, mk);
      const int oi = __shfl_xor(bi, mk);
      if (ov > bv || (ov == bv && oi < bi)) { bv = ov; bi = oi; }
    }
    const int e1 = bi; const float v1 = bv;
    float cv = (eln == e1) ? -1.f : p; int ci = eln;
#pragma unroll
    for (int mk = 1; mk <= 4; mk <<= 1) {
      const float ov = __shfl_xor(cv, mk);
      const int oi = __shfl_xor(ci, mk);
      if (ov > cv || (ov == cv && oi < ci)) { cv = ov; ci = oi; }
    }
    const int e2 = ci; const float v2 = cv;

    if (lane == 0) {
      const float gs = 1.f / (v1 + v2);
      const int li = wave * 4 + tt;
      s_g1[li] = v1 * gs;
      s_g2[li] = v2 * gs;
      s_pb[li] = e1 * 8 + e2;
    }
    impacc += p;
  }
  if (lane < 8) s_imp[wave][eln] = impacc;
  __syncthreads();
  if (tid < 8)
    imp_part[blockIdx.x * 8 + tid] =
        s_imp[0][tid] + s_imp[1][tid] + s_imp[2][tid] + s_imp[3][tid];

  // per-token records (coalesced, block-contiguous)
  if (tid < 16) {
    pbuf[blockIdx.x * 16 + tid] = s_pb[tid];
    ggbuf[blockIdx.x * 16 + tid] = make_float2(s_g1[tid], s_g2[tid]);
  }
  // transposed histograms: histT[c*1024 + blk], c in [0,80)
  if (tid < 80) {
    int c = 0;
    if (tid < 16) {
      const int k = tid >> 3, e = tid & 7;
#pragma unroll
      for (int j = 0; j < 16; ++j)
        c += ((k ? (s_pb[j] & 7) : (s_pb[j] >> 3)) == e) ? 1 : 0;
    } else {
      const int b = tid - 16;
#pragma unroll
      for (int j = 0; j < 16; ++j) c += (s_pb[j] == b) ? 1 : 0;
    }
    histT[tid * 1024 + blockIdx.x] = c;
  }
}

// -------- scan: one block per counter, parallel prefix over 1024 blocks ----
__global__ __launch_bounds__(256) void scan_kernel(
    const int* __restrict__ histT, int* __restrict__ baseT,
    int* __restrict__ cnt, int* __restrict__ cnt_pair) {
  __shared__ int ls[256];
  const int c = blockIdx.x;
  const int t = threadIdx.x;
  const int4 v = ((const int4*)(histT + (c << 10)))[t];
  const int s = v.x + v.y + v.z + v.w;
  ls[t] = s;
  __syncthreads();
#pragma unroll
  for (int off = 1; off < 256; off <<= 1) {
    const int add = (t >= off) ? ls[t - off] : 0;
    __syncthreads();
    ls[t] += add;
    __syncthreads();
  }
  const int incl = ls[t];
  const int excl = incl - s;
  int4 b;
  b.x = excl;
  b.y = excl + v.x;
  b.z = excl + v.x + v.y;
  b.w = excl + v.x + v.y + v.z;
  ((int4*)(baseT + (c << 10)))[t] = b;
  if (t == 255) {
    if (c < 16) cnt[c * 32] = incl;
    else        cnt_pair[(c - 16) * 32] = incl;
  }
}

// -------- scatter (blocks 0..255) + plan (block 256) -----------------------
__global__ __launch_bounds__(256) void scatter_kernel(
    const int* __restrict__ baseT, const int* __restrict__ pbuf,
    const int* __restrict__ cnt_pair,
    int* __restrict__ pairlist, int* __restrict__ fplan,
    int* __restrict__ totals) {
  if (blockIdx.x == 256) {   // plan: 64-token tiles per pair bucket
    __shared__ int uoff[64];
    const int t = threadIdx.x;
    if (t == 0) {
      int a = 0;
      for (int b = 0; b < 64; ++b) { uoff[b] = a; a += (cnt_pair[b * 32] + 63) >> 6; }
      totals[1] = a;
    }
    __syncthreads();
    if (t < 64) {
      const int nb = (cnt_pair[t * 32] + 63) >> 6;
      for (int i = 0; i < nb; ++i) fplan[uoff[t] + i] = (t << 16) | i;
    }
    return;
  }
  const int tid = threadIdx.x;
  const int lane = tid & 63;
  const int wave = tid >> 6;
  const int rb = blockIdx.x * 4 + wave;   // router block, 0..1023
  const int i = lane;
  int pb = 0;
  if (lane < 16) pb = pbuf[rb * 16 + lane];
  int rp = 0;
#pragma unroll
  for (int j = 0; j < 15; ++j) {
    const int q = __shfl(pb, j);
    if (j < i) rp += (q == pb) ? 1 : 0;
  }
  if (lane < 16) {
    const int token = rb * 16 + i;
    const int sp = baseT[((16 + pb) << 10) + rb] + rp;
    pairlist[pb * CAP + sp] = token;
  }
}

// ---- fused expert: 64-token pair tile, y-split output slices --------------
// Phase 1 (redundant per y): H0|H1 = GELU(x@Wd_e1)*g1 | GELU(x@Wd_e2)*g2
//   global_load_lds DMA staging (pre-swizzled sources), m97-style 2-barrier.
// Phase 2: 4 of 8 col slices per block: out = H0@WuA + H1@WuB
__global__ __launch_bounds__(256) void expert_kernel(
    const ushort* __restrict__ xb, const ushort* __restrict__ wdt,
    const ushort* __restrict__ wut,
    const int* __restrict__ cnt_pair, const int* __restrict__ pairlist,
    const float2* __restrict__ ggbuf,
    const int* __restrict__ fplan, const int* __restrict__ totals,
    float* __restrict__ out) {
  if (blockIdx.x >= totals[1]) return;
  const int ent = fplan[blockIdx.x];
  const int b = ent >> 16, tile = ent & 0xffff;
  const int ea = b >> 3, eb = b & 7;
  const int n = cnt_pair[b * 32];
  const int start = tile * 64;
  const int ybase = blockIdx.y * 4;

  __shared__ __align__(16) char smem[49920];
  ushort* As  = (ushort*)(smem);            // 8 KB  phase1
  ushort* BsA = (ushort*)(smem + 8192);     // 8 KB  phase1
  ushort* BsB = (ushort*)(smem + 16384);    // 8 KB  phase1
  ushort* BuA = (ushort*)(smem);            // 16 KB phase2 (aliases As/BsA)
  ushort* BuB = (ushort*)(smem + 16384);    // 16 KB phase2
  ushort* Hs0 = (ushort*)(smem + 32768);    // 8 KB
  ushort* Hs1 = (ushort*)(smem + 40960);    // 8 KB
  int*   toks = (int*)(smem + 49152);
  float* g1s  = (float*)(smem + 49408);
  float* g2s  = (float*)(smem + 49664);

  const int tid = threadIdx.x;
  const int lane = tid & 63;
  const int w = tid >> 6;
  const int wr = w >> 1, wc = w & 1;

  if (tid < 64) {
    int tk = -1; float2 gg = make_float2(0.f, 0.f);
    if (start + tid < n) {
      tk = pairlist[b * CAP + start + tid];
      gg = ggbuf[tk];
    }
    toks[tid] = tk; g1s[tid] = gg.x; g2s[tid] = gg.y;
  }
  __syncthreads();

  // DMA geometry: each wave stages 2 x 1KB batches per 64x64 tile.
  // lane l covers row rsub=l>>3 of its batch, 16B chunk (l&7)*16.
  const int rsub = lane >> 3;
  const int cth  = (lane & 7) * 8;          // ushort col
  const int csw  = cth ^ (rsub << 3);       // pre-swizzled source col (xb)
  const int r0 = (w * 2 + 0) * 8 + rsub;
  const int r1 = (w * 2 + 1) * 8 + rsub;
  const int tk0 = toks[r0], tk1 = toks[r1];
  const ushort* srcA0 = xb + (size_t)(tk0 < 0 ? 0 : tk0) * CDIM + csw;
  const ushort* srcA1 = xb + (size_t)(tk1 < 0 ? 0 : tk1) * CDIM + csw;
  const ushort* wdA = wdt + ((size_t)ea << 16);
  const ushort* wdB = wdt + ((size_t)eb << 16);
  const ushort* srcBA = wdA + (w * 2) * 512 + lane * 8;   // +s*4096 (+512)
  const ushort* srcBB = wdB + (w * 2) * 512 + lane * 8;
  ushort* dA0  = As  + (w * 2 + 0) * 512;
  ushort* dA1  = As  + (w * 2 + 1) * 512;
  ushort* dBA0 = BsA + (w * 2 + 0) * 512;
  ushort* dBA1 = BsA + (w * 2 + 1) * 512;
  ushort* dBB0 = BsB + (w * 2 + 0) * 512;
  ushort* dBB1 = BsB + (w * 2 + 1) * 512;

  f32x4 acc[2][4];
#pragma unroll
  for (int m = 0; m < 2; ++m)
#pragma unroll
    for (int nn = 0; nn < 4; ++nn) acc[m][nn] = (f32x4){0.f, 0.f, 0.f, 0.f};

#pragma unroll 1
  for (int s = 0; s < 16; ++s) {
    __syncthreads();                    // prev step's LDS reads done
    const int ko = s * 64;
    async16(srcA0 + ko, dA0);
    async16(srcA1 + ko, dA1);
    async16(srcBA + s * 4096, dBA0);
    async16(srcBA + s * 4096 + 512, dBA1);
    async16(srcBB + s * 4096, dBB0);
    async16(srcBB + s * 4096 + 512, dBB1);
    __syncthreads();                    // drains DMA (vmcnt before barrier)
    const ushort* Bsx = wc ? BsB : BsA;
#pragma unroll
    for (int kk = 0; kk < 64; kk += 32) {
      const int kb = kk + (lane >> 4) * 8;
      bf16x8 a[2], bb[4];
#pragma unroll
      for (int m = 0; m < 2; ++m) {
        const int row = wr * 32 + m * 16 + (lane & 15);
        a[m] = *(const bf16x8*)&As[row * 64 + (kb ^ ((row & 7) << 3))];
      }
#pragma unroll
      for (int nn = 0; nn < 4; ++nn) {
        const int r = nn * 16 + (lane & 15);
        bb[nn] = *(const bf16x8*)&Bsx[r * 64 + (kb ^ ((r & 7) << 3))];
      }
#pragma unroll
      for (int m = 0; m < 2; ++m)
#pragma unroll
        for (int nn = 0; nn < 4; ++nn)
          acc[m][nn] = __builtin_amdgcn_mfma_f32_16x16x32_bf16(a[m], bb[nn], acc[m][nn], 0, 0, 0);
    }
  }

  // phase-1 epilogue: GELU * gate -> Hs{wc} (swizzled; own rows, no race)
  {
    ushort* Hsx = wc ? Hs1 : Hs0;
    const float* gsx = wc ? g2s : g1s;
#pragma unroll
    for (int m = 0; m < 2; ++m)
#pragma unroll
      for (int nn = 0; nn < 4; ++nn)
#pragma unroll
        for (int q = 0; q < 4; ++q) {
          const int slot = wr * 32 + m * 16 + (lane >> 4) * 4 + q;
          const int r = nn * 16 + (lane & 15);
          const float v = acc[m][nn][q];
          const float ge = 0.5f * v * (1.f + erff(v * 0.70710678118654752f));
          Hsx[slot * 64 + (r ^ ((slot & 7) << 3))] = f2bf(ge * gsx[slot]);
        }
  }

  // phase 2: 4 slices, Bu staged by DMA (pre-swizzled wut tiles)
  const ushort* wuA = wut + ((size_t)ea << 16);
  const ushort* wuB = wut + ((size_t)eb << 16);
  const ushort* suA = wuA + (w * 4) * 512 + lane * 8;   // +n0*8192 +bq*512
  const ushort* suB = wuB + (w * 4) * 512 + lane * 8;

#pragma unroll 1
  for (int j = 0; j < 4; ++j) {
    const int n0 = ybase + j;
    __syncthreads();                    // Hs visible / prev Bu reads done
#pragma unroll
    for (int bq = 0; bq < 4; ++bq) {
      async16(suA + (size_t)n0 * 8192 + bq * 512, BuA + (w * 4 + bq) * 512);
      async16(suB + (size_t)n0 * 8192 + bq * 512, BuB + (w * 4 + bq) * 512);
    }
    __syncthreads();                    // drains DMA
    f32x4 uac[2][4];
#pragma unroll
    for (int m = 0; m < 2; ++m)
#pragma unroll
      for (int nn = 0; nn < 4; ++nn) uac[m][nn] = (f32x4){0.f, 0.f, 0.f, 0.f};
    // pass A: H0 @ WuA
#pragma unroll
    for (int kk = 0; kk < 64; kk += 32) {
      const int kb = kk + (lane >> 4) * 8;
      bf16x8 a[2], bb[4];
#pragma unroll
      for (int m = 0; m < 2; ++m) {
        const int row = wr * 32 + m * 16 + (lane & 15);
        a[m] = *(const bf16x8*)&Hs0[row * 64 + (kb ^ ((row & 7) << 3))];
      }
#pragma unroll
      for (int nn = 0; nn < 4; ++nn) {
        const int c = wc * 64 + nn * 16 + (lane & 15);
        bb[nn] = *(const bf16x8*)&BuA[c * 64 + (kb ^ ((c & 7) << 3))];
      }
#pragma unroll
      for (int m = 0; m < 2; ++m)
#pragma unroll
        for (int nn = 0; nn < 4; ++nn)
          uac[m][nn] = __builtin_amdgcn_mfma_f32_16x16x32_bf16(a[m], bb[nn], uac[m][nn], 0, 0, 0);
    }
    // pass B: H1 @ WuB (accumulate)
#pragma unroll
    for (int kk = 0; kk < 64; kk += 32) {
      const int kb = kk + (lane >> 4) * 8;
      bf16x8 a[2], bb[4];
#pragma unroll
      for (int m = 0; m < 2; ++m) {
        const int row = wr * 32 + m * 16 + (lane & 15);
        a[m] = *(const bf16x8*)&Hs1[row * 64 + (kb ^ ((row & 7) << 3))];
      }
#pragma unroll
      for (int nn = 0; nn < 4; ++nn) {
        const int c = wc * 64 + nn * 16 + (lane & 15);
        bb[nn] = *(const bf16x8*)&BuB[c * 64 + (kb ^ ((c & 7) << 3))];
      }
#pragma unroll
      for (int m = 0; m < 2; ++m)
#pragma unroll
        for (int nn = 0; nn < 4; ++nn)
          uac[m][nn] = __builtin_amdgcn_mfma_f32_16x16x32_bf16(a[m], bb[nn], uac[m][nn], 0, 0, 0);
    }
    // store this 128-col slice
#pragma unroll
    for (int m = 0; m < 2; ++m)
#pragma unroll
      for (int q = 0; q < 4; ++q) {
        const int slot = wr * 32 + m * 16 + (lane >> 4) * 4 + q;
        const int tk = toks[slot];
        if (tk >= 0) {
          float* orow = out + (size_t)tk * CDIM + n0 * 128 + wc * 64 + (lane & 15);
#pragma unroll
          for (int nn = 0; nn < 4; ++nn) orow[nn * 16] = uac[m][nn][q];
        }
      }
  }
}

// ---------------- aux: deterministic reduce of per-block importance --------
__global__ __launch_bounds__(256) void aux_kernel(
    const int* __restrict__ cnt, const float* __restrict__ imp_part,
    float* __restrict__ out_aux) {
  __shared__ float red[256];
  __shared__ float tot[NEXP];
  const int t = threadIdx.x;
  const int e = t & 7, b0 = t >> 3;
  float s = 0.f;
  for (int j = 0; j < NBLK_R / 32; ++j)
    s += imp_part[(b0 + 32 * j) * 8 + e];
  red[t] = s;
  __syncthreads();
  if (t < 8) {
    float tt = 0.f;
    for (int w = 0; w < 32; ++w) tt += red[w * 8 + t];
    tot[t] = tt;
  }
  __syncthreads();
  if (t == 0) {
    float a = 0.f;
#pragma unroll
    for (int ee = 0; ee < NEXP; ++ee)
      a += (tot[ee] / (float)TOKS) *
           ((float)(cnt[ee * 32] + cnt[(NEXP + ee) * 32]) / (float)(2 * TOKS));
    out_aux[0] = 0.001f * 8.f * a;
  }
}

extern "C" void kernel_launch(void* const* d_in, const int* in_sizes, int n_in,
                              void* d_out, int out_size, void* d_ws, size_t ws_size,
                              hipStream_t stream) {
  const float* x   = (const float*)d_in[0];
  const float* rw  = (const float*)d_in[1];
  const float* rb  = (const float*)d_in[2];
  const float* Wd  = (const float*)d_in[3];
  const float* Wu  = (const float*)d_in[4];
  const int* key_id = (const int*)d_in[5];
  float* out = (float*)d_out;

  char* ws = (char*)d_ws;
  int*    cnt      = (int*)ws;                    // 2 KB  (16 x 128B)
  int*    cnt_pair = (int*)(ws + 2048);           // 8 KB  (64 x 128B)
  int*    totals   = (int*)(ws + 10240);          // 8 B
  float*  imp_part = (float*)(ws + 16384);        // 32 KB
  int*    fplan    = (int*)(ws + 49152);          // ~2 KB
  ushort* wdt      = (ushort*)(ws + 2162688);     // 1 MB
  ushort* wut      = (ushort*)(ws + 3211264);     // 1 MB
  ushort* xb       = (ushort*)(ws + 4259840);     // 32 MB -> 37814272
  float*  rw_p     = (float*)(ws + 37814272);     // 32 KB -> 37847040
  int*    pairlist = (int*)(ws + 37847040);       // 4 MB  -> 42041344
  // router scratch (consumed by scan/scatter before expert_kernel runs)
  int*    histT = (int*)(ws + 42041344);                // 320 KB
  int*    baseT = (int*)(ws + 42041344 + 327680);       // 320 KB
  int*    pbuf  = (int*)(ws + 42041344 + 655360);       // 64 KB
  float2* ggbuf = (float2*)(ws + 42041344 + 720896);    // 128 KB (live into expert)

  convert_kernel<<<1032, 256, 0, stream>>>(Wd, Wu, rw, key_id, wdt, wut, rw_p);
  router_kernel<<<NBLK_R, 256, 0, stream>>>(x, rw_p, rb, key_id, imp_part,
                                            pbuf, ggbuf, histT, xb);
  scan_kernel<<<80, 256, 0, stream>>>(histT, baseT, cnt, cnt_pair);
  scatter_kernel<<<257, 256, 0, stream>>>(baseT, pbuf, cnt_pair,
                                          pairlist, fplan, totals);
  expert_kernel<<<dim3(FT_MAX, NSPLIT), 256, 0, stream>>>(
      xb, wdt, wut, cnt_pair, pairlist, ggbuf, fplan, totals, out);
  aux_kernel<<<1, 256, 0, stream>>>(cnt, imp_part, out + (size_t)TOKS * CDIM);
}